// Round 7
// baseline (216.278 us; speedup 1.0000x reference)
//
#include <hip/hip_runtime.h>

// ---------------------------------------------------------------------------
// GNN discriminator, 5 dispatches:
//   memset cnt -> [bucket-fill || mm1] -> mm2+gather -> mm3+gather
//   -> pool+gather+classifier
// S[N][64] bf16 (self) + M[N][64] fp8-e4m3 (message) split (R19: -9us,
// absmax 0.0625; byte-bound theory only partially held).
// R20/R21: nt-hints in gather kernels ONLY (cnt/csr/Sprev loads, Sout/Mout
// stores). Mechanism: each pass streams ~22MB touch-once through L2 while
// randomly re-reading the 3.2MB M hot set; post-fp8 M fits the 4MB XCD L2,
// so protecting L2 from streaming evictions now HAS a mechanism (R15's nt
// failed when hot set was 6.4MB > L2 — regime changed, re-test). M gather
// loads stay cacheable. Fill untouched (R15 regression was fill VGPR bloat).
// R21 fixes R20's compile error: __builtin_nontemporal_load requires
// ext_vector_type pointers, not HIP_vector_type uint4.
// History: R18 masked-idx clamp NEUTRAL (kept: guarantees idx<N). Fill at
// ~50us atomic floor (R6-R12; ~51MB fabric churn from 800K atomics).
// Gather: 16 loads in flight, fmaf-masked (R10/R14 constraints).
// ---------------------------------------------------------------------------

#define CAP 64

typedef __attribute__((ext_vector_type(8))) short short8;   // 8 bf16 (4 VGPR)
typedef __attribute__((ext_vector_type(4))) float floatx4;  // MFMA C/D
typedef __attribute__((ext_vector_type(2))) float floatx2;  // cvt_pk result
typedef __attribute__((ext_vector_type(4))) unsigned uintx4; // nt-load vehicle

__device__ __forceinline__ unsigned short f2bf(float f) {
    union { float f; unsigned u; } v; v.f = f;
    unsigned r = v.u + 0x7FFF + ((v.u >> 16) & 1);   // round-to-nearest-even
    return (unsigned short)(r >> 16);
}

// f32 -> fp8 e4m3 (OCP, RNE) via packed HW convert; take byte 0.
__device__ __forceinline__ unsigned char f2fp8(float f) {
    int v = __builtin_amdgcn_cvt_pk_fp8_f32(f, 0.f, 0, false);
    return (unsigned char)(v & 0xff);
}

// Non-temporal (no L2 allocate) streaming accessors for the gather passes.
// Must go through ext_vector_type (clang builtin constraint).
__device__ __forceinline__ uintx4 ldnt_u4(const void* p) {
    return __builtin_nontemporal_load((const uintx4*)p);
}
__device__ __forceinline__ int ldnt_i(const int* p) {
    return __builtin_nontemporal_load(p);
}
__device__ __forceinline__ void stnt_u16(unsigned short* p, unsigned short v) {
    __builtin_nontemporal_store(v, p);
}
__device__ __forceinline__ void stnt_u8(unsigned char* p, unsigned char v) {
    __builtin_nontemporal_store(v, p);
}

// 8 fp8 (packed in uint2) -> f32, fmaf-accumulate with scale s.
__device__ __forceinline__ void fp8x8fma(float* t, uint2 w, float s) {
    floatx2 p;
    p = __builtin_amdgcn_cvt_pk_f32_fp8(w.x, false);
    t[0] = fmaf(p[0], s, t[0]); t[1] = fmaf(p[1], s, t[1]);
    p = __builtin_amdgcn_cvt_pk_f32_fp8(w.x, true);
    t[2] = fmaf(p[0], s, t[2]); t[3] = fmaf(p[1], s, t[3]);
    p = __builtin_amdgcn_cvt_pk_f32_fp8(w.y, false);
    t[4] = fmaf(p[0], s, t[4]); t[5] = fmaf(p[1], s, t[5]);
    p = __builtin_amdgcn_cvt_pk_f32_fp8(w.y, true);
    t[6] = fmaf(p[0], s, t[6]); t[7] = fmaf(p[1], s, t[7]);
}

__device__ __forceinline__ void bf8unpack_x(uintx4 w, float* s) {
    s[0] = __uint_as_float(w.x << 16);
    s[1] = __uint_as_float(w.x & 0xffff0000u);
    s[2] = __uint_as_float(w.y << 16);
    s[3] = __uint_as_float(w.y & 0xffff0000u);
    s[4] = __uint_as_float(w.z << 16);
    s[5] = __uint_as_float(w.z & 0xffff0000u);
    s[6] = __uint_as_float(w.w << 16);
    s[7] = __uint_as_float(w.w & 0xffff0000u);
}

// Deep gather over M (fp8 msg rows, 64B): 16 independent 8B loads in flight,
// fmaf-masked accumulate. Masked slots (j >= c) clamped to idx 0. cnt/csr
// are touch-once per pass -> nt; M rows are the hot set -> cacheable.
__device__ __forceinline__ void gather_deep(
    const unsigned char* __restrict__ M, const int* __restrict__ cnt,
    const unsigned short* __restrict__ csr, int node, int cg, float* acc8, int N)
{
    const int nodeC = node < N ? node : 0;
    int c = node < N ? ldnt_i(cnt + nodeC) : 0;
    if (c > CAP) c = CAP;
    const unsigned short* bp = csr + (size_t)nodeC * CAP;

    uintx4 q0 = ldnt_u4(bp);
    uintx4 q1 = ldnt_u4(bp + 8);
    unsigned idx[16];
    idx[0]  = q0.x & 0xffff; idx[1]  = q0.x >> 16;
    idx[2]  = q0.y & 0xffff; idx[3]  = q0.y >> 16;
    idx[4]  = q0.z & 0xffff; idx[5]  = q0.z >> 16;
    idx[6]  = q0.w & 0xffff; idx[7]  = q0.w >> 16;
    idx[8]  = q1.x & 0xffff; idx[9]  = q1.x >> 16;
    idx[10] = q1.y & 0xffff; idx[11] = q1.y >> 16;
    idx[12] = q1.z & 0xffff; idx[13] = q1.z >> 16;
    idx[14] = q1.w & 0xffff; idx[15] = q1.w >> 16;
#pragma unroll
    for (int j = 0; j < 16; ++j)
        if (j >= c) idx[j] = 0;        // clamp masked slots to the hot line

    uint2 w[16];
#pragma unroll
    for (int j = 0; j < 16; ++j)
        w[j] = *(const uint2*)&M[(size_t)idx[j] * 64 + cg * 8];

    float a[8], b[8];
#pragma unroll
    for (int j = 0; j < 8; ++j) { a[j] = 0.f; b[j] = 0.f; }
#pragma unroll
    for (int j = 0; j < 16; ++j)
        fp8x8fma((j & 1) ? b : a, w[j], (j < c) ? 1.f : 0.f);

    for (int base = 16; base < c; base += 8) {
        uintx4 q = ldnt_u4(bp + base);
        unsigned id2[8];
        id2[0] = q.x & 0xffff; id2[1] = q.x >> 16;
        id2[2] = q.y & 0xffff; id2[3] = q.y >> 16;
        id2[4] = q.z & 0xffff; id2[5] = q.z >> 16;
        id2[6] = q.w & 0xffff; id2[7] = q.w >> 16;
#pragma unroll
        for (int j = 0; j < 8; ++j)
            if (base + j >= c) id2[j] = 0;
        uint2 w2[8];
#pragma unroll
        for (int j = 0; j < 8; ++j)
            w2[j] = *(const uint2*)&M[(size_t)id2[j] * 64 + cg * 8];
#pragma unroll
        for (int j = 0; j < 8; ++j)
            fp8x8fma((j & 1) ? b : a, w2[j], (base + j < c) ? 1.f : 0.f);
    }
#pragma unroll
    for (int j = 0; j < 8; ++j) acc8[j] = a[j] + b[j];
}

// ---------------- layer 1: [bucket fill || mm1 (MFMA)] ----------------
// UNTOUCHED cache policy (R15 lesson: nt here bloats VGPR, regresses fill).

__device__ __forceinline__ void mm1_body(
    const float* __restrict__ Xraw,
    const float* __restrict__ W1, const float* __restrict__ W2,
    unsigned short* __restrict__ S, unsigned char* __restrict__ M,
    int N, int blk)
{
    __shared__ __align__(16) unsigned short Xs[64][72];
    __shared__ __align__(16) unsigned short Ws[128][72];
    const int tid  = threadIdx.x;
    const int lane = tid & 63;
    const int wv   = tid >> 6;
    const int lrow = lane & 15;
    const int quad = lane >> 4;
    const int row0 = blk * 64;

    floatx4 acc[8];
#pragma unroll
    for (int i = 0; i < 8; ++i) acc[i] = (floatx4){0.f, 0.f, 0.f, 0.f};

    const int xr  = tid >> 2;
    const int xk  = (tid & 3) * 16;
    const int gxr = row0 + xr;

    for (int ko = 0; ko < 128; ko += 64) {
#pragma unroll
        for (int q = 0; q < 4; ++q) {
            float4 v = make_float4(0.f, 0.f, 0.f, 0.f);
            if (gxr < N) v = *(const float4*)&Xraw[(size_t)gxr * 128 + ko + xk + q * 4];
            ushort4 p;
            p.x = f2bf(v.x); p.y = f2bf(v.y); p.z = f2bf(v.z); p.w = f2bf(v.w);
            *(ushort4*)&Xs[xr][xk + q * 4] = p;
        }
#pragma unroll
        for (int i = 0; i < 2; ++i) {
            int s  = tid + i * 256;
            int k0 = (s & 15) * 4;
            int c0 = (s >> 4) * 4;
            float wr[4][4];
#pragma unroll
            for (int r = 0; r < 4; ++r) {
                int gk = ko + k0 + r;
                float4 t4 = (c0 < 64) ? *(const float4*)&W1[(size_t)gk * 64 + c0]
                                      : *(const float4*)&W2[(size_t)gk * 64 + (c0 - 64)];
                wr[r][0] = t4.x; wr[r][1] = t4.y; wr[r][2] = t4.z; wr[r][3] = t4.w;
            }
#pragma unroll
            for (int j = 0; j < 4; ++j) {
                ushort4 col;
                col.x = f2bf(wr[0][j]); col.y = f2bf(wr[1][j]);
                col.z = f2bf(wr[2][j]); col.w = f2bf(wr[3][j]);
                *(ushort4*)&Ws[c0 + j][k0] = col;
            }
        }
        __syncthreads();

#pragma unroll
        for (int kc = 0; kc < 2; ++kc) {
            int kofs = kc * 32 + quad * 8;
            short8 a = *(const short8*)&Xs[wv * 16 + lrow][kofs];
#pragma unroll
            for (int ct = 0; ct < 8; ++ct) {
                short8 b = *(const short8*)&Ws[ct * 16 + lrow][kofs];
                acc[ct] = __builtin_amdgcn_mfma_f32_16x16x32_bf16(a, b, acc[ct], 0, 0, 0);
            }
        }
        __syncthreads();
    }

    const int orow = row0 + wv * 16 + quad * 4;
#pragma unroll
    for (int ct = 0; ct < 8; ++ct) {
        int col = ct * 16 + lrow;
#pragma unroll
        for (int r = 0; r < 4; ++r) {
            int gr = orow + r;
            if (gr < N) {
                if (ct < 4) S[(size_t)gr * 64 + col] = f2bf(acc[ct][r]);
                else        M[(size_t)gr * 64 + (col - 64)] = f2fp8(acc[ct][r]);
            }
        }
    }
}

// One-pass bucket fill, ILP-8 (R9-proven).
__device__ __forceinline__ void fill_body(
    const int* __restrict__ ei, int* __restrict__ cnt,
    unsigned short* __restrict__ csr, int E, int bid, int stride)
{
    int base = bid * 256 + threadIdx.x;
    int e[8], d[8], s[8], p[8];
    bool v[8];
#pragma unroll
    for (int j = 0; j < 8; ++j) {
        e[j] = base + j * stride;
        v[j] = e[j] < E;
        if (v[j]) {
            d[j] = ei[E + e[j]];
            s[j] = ei[e[j]];
        }
    }
#pragma unroll
    for (int j = 0; j < 8; ++j)
        if (v[j]) p[j] = atomicAdd(&cnt[d[j]], 1);
#pragma unroll
    for (int j = 0; j < 8; ++j)
        if (v[j] && p[j] < CAP) csr[(size_t)d[j] * CAP + p[j]] = (unsigned short)s[j];
}

__global__ __launch_bounds__(256) void mm1_fill_kernel(
    const float* __restrict__ Xraw,
    const float* __restrict__ W1, const float* __restrict__ W2,
    unsigned short* __restrict__ S, unsigned char* __restrict__ M, int N,
    const int* __restrict__ ei, int* __restrict__ cnt,
    unsigned short* __restrict__ csr, int E, int edgeBlocks)
{
    if ((int)blockIdx.x < edgeBlocks) {
        fill_body(ei, cnt, csr, E, blockIdx.x, edgeBlocks * 256);
    } else {
        mm1_body(Xraw, W1, W2, S, M, N, (int)blockIdx.x - edgeBlocks);
    }
}

// ---------------- layers 2,3: gather fused into GEMM staging ----------------
// 256 threads, 32 slots x 2 rows (R13-proven best shape).
__global__ __launch_bounds__(256) void mm_gather_kernel(
    const unsigned short* __restrict__ Sprev, const unsigned char* __restrict__ Mprev,
    const int* __restrict__ cnt, const unsigned short* __restrict__ csr,
    const float* __restrict__ W1, const float* __restrict__ W2,
    unsigned short* __restrict__ Sout, unsigned char* __restrict__ Mout, int N)
{
    __shared__ __align__(16) unsigned short Xs[64][72];
    __shared__ __align__(16) unsigned short Ws[128][72];
    const int tid  = threadIdx.x;
    const int lane = tid & 63;
    const int wv   = tid >> 6;
    const int lrow = lane & 15;
    const int quad = lane >> 4;
    const int row0 = blockIdx.x * 64;
    const int eg   = lane >> 3;
    const int cg   = lane & 7;

    // ---- stage W (64k x 128c, transposed bf16) ----
#pragma unroll
    for (int i = 0; i < 2; ++i) {
        int s  = tid + i * 256;
        int k0 = (s & 15) * 4;
        int c0 = (s >> 4) * 4;
        float wr[4][4];
#pragma unroll
        for (int r = 0; r < 4; ++r) {
            int gk = k0 + r;
            float4 t4 = (c0 < 64) ? *(const float4*)&W1[(size_t)gk * 64 + c0]
                                  : *(const float4*)&W2[(size_t)gk * 64 + (c0 - 64)];
            wr[r][0] = t4.x; wr[r][1] = t4.y; wr[r][2] = t4.z; wr[r][3] = t4.w;
        }
#pragma unroll
        for (int j = 0; j < 4; ++j) {
            ushort4 col;
            col.x = f2bf(wr[0][j]); col.y = f2bf(wr[1][j]);
            col.z = f2bf(wr[2][j]); col.w = f2bf(wr[3][j]);
            *(ushort4*)&Ws[c0 + j][k0] = col;
        }
    }

    // ---- gather-stage X: act = relu(self + gather(msg)) -> bf16 LDS ----
#pragma unroll
    for (int half = 0; half < 2; ++half) {
        int xrow = half * 32 + wv * 8 + eg;
        int node = row0 + xrow;
        float g8[8];
        gather_deep(Mprev, cnt, csr, node, cg, g8, N);
        float r8[8];
        if (node < N) {
            uintx4 h = ldnt_u4(&Sprev[(size_t)node * 64 + cg * 8]);
            float s8[8];
            bf8unpack_x(h, s8);
#pragma unroll
            for (int j = 0; j < 8; ++j) r8[j] = fmaxf(g8[j] + s8[j], 0.f);
        } else {
#pragma unroll
            for (int j = 0; j < 8; ++j) r8[j] = 0.f;
        }
        ushort4 p0, p1;
        p0.x = f2bf(r8[0]); p0.y = f2bf(r8[1]); p0.z = f2bf(r8[2]); p0.w = f2bf(r8[3]);
        p1.x = f2bf(r8[4]); p1.y = f2bf(r8[5]); p1.z = f2bf(r8[6]); p1.w = f2bf(r8[7]);
        *(ushort4*)&Xs[xrow][cg * 8]     = p0;
        *(ushort4*)&Xs[xrow][cg * 8 + 4] = p1;
    }
    __syncthreads();

    // ---- MFMA ----
    floatx4 acc[8];
#pragma unroll
    for (int i = 0; i < 8; ++i) acc[i] = (floatx4){0.f, 0.f, 0.f, 0.f};
#pragma unroll
    for (int kc = 0; kc < 2; ++kc) {
        int kofs = kc * 32 + quad * 8;
        short8 a = *(const short8*)&Xs[wv * 16 + lrow][kofs];
#pragma unroll
        for (int ct = 0; ct < 8; ++ct) {
            short8 b = *(const short8*)&Ws[ct * 16 + lrow][kofs];
            acc[ct] = __builtin_amdgcn_mfma_f32_16x16x32_bf16(a, b, acc[ct], 0, 0, 0);
        }
    }

    // ---- epilogue: bf16 self row + fp8 msg row per node (nt stores) ----
    const int orow = row0 + wv * 16 + quad * 4;
#pragma unroll
    for (int ct = 0; ct < 8; ++ct) {
        int col = ct * 16 + lrow;
#pragma unroll
        for (int r = 0; r < 4; ++r) {
            int gr = orow + r;
            if (gr < N) {
                if (ct < 4) stnt_u16(&Sout[(size_t)gr * 64 + col], f2bf(acc[ct][r]));
                else        stnt_u8(&Mout[(size_t)gr * 64 + (col - 64)], f2fp8(acc[ct][r]));
            }
        }
    }
}

// ---------------- pool + deep gather + classifier ----------------
// One block (512 threads, 64 node-slots) per graph; lane owns 8 cols.
__global__ __launch_bounds__(512) void pool_gather_cls_kernel(
    const unsigned short* __restrict__ S, const unsigned char* __restrict__ M,
    const int* __restrict__ cnt, const unsigned short* __restrict__ csr,
    const int* __restrict__ batch,
    const float* __restrict__ cW1, const float* __restrict__ cb1,
    const float* __restrict__ cW2, const float* __restrict__ cb2,
    float* __restrict__ out, int N)
{
    int g  = blockIdx.x;
    int t  = threadIdx.x;
    int wv = t >> 6;
    int lane = t & 63;
    int eg = lane >> 3;
    int cg = lane & 7;
    int slot = wv * 8 + eg;      // 0..63

    int lo = 0, hi = N;
    while (lo < hi) { int mid = (lo + hi) >> 1; if (batch[mid] < g) lo = mid + 1; else hi = mid; }
    int start = lo;
    hi = N;
    while (lo < hi) { int mid = (lo + hi) >> 1; if (batch[mid] < g + 1) lo = mid + 1; else hi = mid; }
    int end = lo;

    float p8[8];
#pragma unroll
    for (int j = 0; j < 8; ++j) p8[j] = 0.f;

    for (int r = start + slot; r < end; r += 64) {
        float g8[8];
        gather_deep(M, cnt, csr, r, cg, g8, N);
        uintx4 h = ldnt_u4(&S[(size_t)r * 64 + cg * 8]);
        float s8[8];
        bf8unpack_x(h, s8);
#pragma unroll
        for (int j = 0; j < 8; ++j) p8[j] += fmaxf(g8[j] + s8[j], 0.f);
    }

    __shared__ float part[64][64];
    __shared__ float pooled[64];
#pragma unroll
    for (int j = 0; j < 8; ++j) part[slot][cg * 8 + j] = p8[j];
    __syncthreads();

    if (t < 64) {
        float s = 0.f;
#pragma unroll 8
        for (int k = 0; k < 64; ++k) s += part[k][t];
        float c_ = (float)((end - start) > 0 ? (end - start) : 1);
        pooled[t] = s / c_;
    }
    __syncthreads();
    if (t < 64) {
        float a = cb1[t];
#pragma unroll 8
        for (int k = 0; k < 64; ++k) a += pooled[k] * cW1[k * 64 + t];
        a = fmaxf(a, 0.f);
        float o = a * cW2[t];
#pragma unroll
        for (int off_ = 32; off_ > 0; off_ >>= 1) o += __shfl_down(o, off_);
        if (t == 0) out[g] = o + cb2[0];
    }
}

extern "C" void kernel_launch(void* const* d_in, const int* in_sizes, int n_in,
                              void* d_out, int out_size, void* d_ws, size_t ws_size,
                              hipStream_t stream)
{
    const float* x     = (const float*)d_in[0];
    const int*   ei    = (const int*)d_in[1];
    const int*   batch = (const int*)d_in[2];
    const float* W1_1  = (const float*)d_in[3];
    const float* W2_1  = (const float*)d_in[4];
    const float* W1_2  = (const float*)d_in[5];
    const float* W2_2  = (const float*)d_in[6];
    const float* W1_3  = (const float*)d_in[7];
    const float* W2_3  = (const float*)d_in[8];
    const float* cW1   = (const float*)d_in[9];
    const float* cb1   = (const float*)d_in[10];
    const float* cW2   = (const float*)d_in[11];
    const float* cb2   = (const float*)d_in[12];
    float* out = (float*)d_out;

    const int N = in_sizes[0] / 128;
    const int E = in_sizes[1] / 2;
    const int G = out_size;

    // Workspace layout (all dereferenced gather idx < N after R18 clamp):
    //   MA[N][64] fp8 | MB[N][64] fp8 | SA[N][64] bf16 | SB[N][64] bf16
    //   | cnt[N] | csr[N][CAP] u16      (total ~25.8 MB)
    unsigned char*  MA  = (unsigned char*)d_ws;                     // N*64 fp8
    unsigned char*  MB  = MA + (size_t)N * 64;                      // N*64 fp8
    unsigned short* SA  = (unsigned short*)(MB + (size_t)N * 64);   // N*64 bf16
    unsigned short* SB  = SA + (size_t)N * 64;                      // N*64 bf16
    int*            cnt = (int*)(SB + (size_t)N * 64);              // N
    unsigned short* csr = (unsigned short*)(cnt + N);               // N*CAP

    const int mmGrid     = (N + 63) / 64;
    const int edgeBlocks = (E + 2047) / 2048;    // ILP-8

    (void)hipMemsetAsync(cnt, 0, (size_t)N * sizeof(int), stream);

    // layer 1: [bucket fill || mm1] -> SA,MA
    mm1_fill_kernel<<<edgeBlocks + mmGrid, 256, 0, stream>>>(
        x, W1_1, W2_1, SA, MA, N, ei, cnt, csr, E, edgeBlocks);
    // layer 2: gather(MA) fused into GEMM -> SB,MB
    mm_gather_kernel<<<mmGrid, 256, 0, stream>>>(
        SA, MA, cnt, csr, W1_2, W2_2, SB, MB, N);
    // layer 3: gather(MB) fused into GEMM -> SA,MA
    mm_gather_kernel<<<mmGrid, 256, 0, stream>>>(
        SB, MB, cnt, csr, W1_3, W2_3, SA, MA, N);
    // pool (gather(MA) + relu(self+.) mean) + classifier
    pool_gather_cls_kernel<<<G, 512, 0, stream>>>(
        SA, MA, cnt, csr, batch, cW1, cb1, cW2, cb2, out, N);
}

// Round 8
// 205.599 us; speedup vs baseline: 1.0519x; 1.0519x over previous
//
#include <hip/hip_runtime.h>

// ---------------------------------------------------------------------------
// GNN discriminator, 5 dispatches:
//   memset cnt -> [bucket-fill || mm1] -> mm2+gather -> mm3+gather
//   -> pool+gather+classifier
// S[N][64] bf16 (self) + M[N][64] fp8-e4m3 (message) split (R19: -9us,
// absmax 0.0625).
// R22: gather passes are latency*concurrency bound (R19: bytes/2 -> only
// -9us; R15/R21: cache policy neutral/negative => MLP is the lever).
// mm_gather now fuses both per-thread node gathers into gather_deep2:
// cnt+csr for both halves issued together, then ALL 32 M-loads in flight
// before any FMA. In-flight/CU: 20 waves x16 -> 16 waves x32 (+60%) even
// with the VGPR-driven occupancy drop. Pool/fill untouched.
// History: R21 nt-hints REGRESSED +10us (pool pathological under profiling;
// L2-protection falsified in both regimes). R18 masked-idx clamp NEUTRAL
// (kept: guarantees idx<N). Fill at ~50us atomic floor (R6-R12).
// R10: exec-predication regresses; R14: >32 slots/block regresses.
// ---------------------------------------------------------------------------

#define CAP 64

typedef __attribute__((ext_vector_type(8))) short short8;   // 8 bf16 (4 VGPR)
typedef __attribute__((ext_vector_type(4))) float floatx4;  // MFMA C/D
typedef __attribute__((ext_vector_type(2))) float floatx2;  // cvt_pk result

__device__ __forceinline__ unsigned short f2bf(float f) {
    union { float f; unsigned u; } v; v.f = f;
    unsigned r = v.u + 0x7FFF + ((v.u >> 16) & 1);   // round-to-nearest-even
    return (unsigned short)(r >> 16);
}

// f32 -> fp8 e4m3 (OCP, RNE) via packed HW convert; take byte 0.
__device__ __forceinline__ unsigned char f2fp8(float f) {
    int v = __builtin_amdgcn_cvt_pk_fp8_f32(f, 0.f, 0, false);
    return (unsigned char)(v & 0xff);
}

// 8 fp8 (packed in uint2) -> f32, fmaf-accumulate with scale s.
__device__ __forceinline__ void fp8x8fma(float* t, uint2 w, float s) {
    floatx2 p;
    p = __builtin_amdgcn_cvt_pk_f32_fp8(w.x, false);
    t[0] = fmaf(p[0], s, t[0]); t[1] = fmaf(p[1], s, t[1]);
    p = __builtin_amdgcn_cvt_pk_f32_fp8(w.x, true);
    t[2] = fmaf(p[0], s, t[2]); t[3] = fmaf(p[1], s, t[3]);
    p = __builtin_amdgcn_cvt_pk_f32_fp8(w.y, false);
    t[4] = fmaf(p[0], s, t[4]); t[5] = fmaf(p[1], s, t[5]);
    p = __builtin_amdgcn_cvt_pk_f32_fp8(w.y, true);
    t[6] = fmaf(p[0], s, t[6]); t[7] = fmaf(p[1], s, t[7]);
}

__device__ __forceinline__ void bf8unpack(uint4 w, float* s) {
    s[0] = __uint_as_float(w.x << 16);
    s[1] = __uint_as_float(w.x & 0xffff0000u);
    s[2] = __uint_as_float(w.y << 16);
    s[3] = __uint_as_float(w.y & 0xffff0000u);
    s[4] = __uint_as_float(w.z << 16);
    s[5] = __uint_as_float(w.z & 0xffff0000u);
    s[6] = __uint_as_float(w.w << 16);
    s[7] = __uint_as_float(w.w & 0xffff0000u);
}

__device__ __forceinline__ void unpack16(uint4 q0, uint4 q1, unsigned* idx) {
    idx[0]  = q0.x & 0xffff; idx[1]  = q0.x >> 16;
    idx[2]  = q0.y & 0xffff; idx[3]  = q0.y >> 16;
    idx[4]  = q0.z & 0xffff; idx[5]  = q0.z >> 16;
    idx[6]  = q0.w & 0xffff; idx[7]  = q0.w >> 16;
    idx[8]  = q1.x & 0xffff; idx[9]  = q1.x >> 16;
    idx[10] = q1.y & 0xffff; idx[11] = q1.y >> 16;
    idx[12] = q1.z & 0xffff; idx[13] = q1.z >> 16;
    idx[14] = q1.w & 0xffff; idx[15] = q1.w >> 16;
}

// Tail for nodes with c > 16 (sequential; ~10% of traffic).
__device__ __forceinline__ void gather_tail(
    const unsigned char* __restrict__ M, const uint4* __restrict__ bv,
    int c, int cg, float* a, float* b)
{
    for (int base = 16; base < c; base += 8) {
        uint4 q = bv[base >> 3];
        unsigned id2[8];
        id2[0] = q.x & 0xffff; id2[1] = q.x >> 16;
        id2[2] = q.y & 0xffff; id2[3] = q.y >> 16;
        id2[4] = q.z & 0xffff; id2[5] = q.z >> 16;
        id2[6] = q.w & 0xffff; id2[7] = q.w >> 16;
#pragma unroll
        for (int j = 0; j < 8; ++j)
            if (base + j >= c) id2[j] = 0;
        uint2 w2[8];
#pragma unroll
        for (int j = 0; j < 8; ++j)
            w2[j] = *(const uint2*)&M[(size_t)id2[j] * 64 + cg * 8];
#pragma unroll
        for (int j = 0; j < 8; ++j)
            fp8x8fma((j & 1) ? b : a, w2[j], (base + j < c) ? 1.f : 0.f);
    }
}

// Single-node deep gather (pool kernel). 16 loads in flight, fmaf-masked.
__device__ __forceinline__ void gather_deep(
    const unsigned char* __restrict__ M, const int* __restrict__ cnt,
    const unsigned short* __restrict__ csr, int node, int cg, float* acc8, int N)
{
    const int nodeC = node < N ? node : 0;
    int c = node < N ? cnt[nodeC] : 0;
    if (c > CAP) c = CAP;
    const uint4* bv = (const uint4*)(csr + (size_t)nodeC * CAP);

    uint4 q0 = bv[0];
    uint4 q1 = bv[1];
    unsigned idx[16];
    unpack16(q0, q1, idx);
#pragma unroll
    for (int j = 0; j < 16; ++j)
        if (j >= c) idx[j] = 0;        // clamp masked slots to the hot line

    uint2 w[16];
#pragma unroll
    for (int j = 0; j < 16; ++j)
        w[j] = *(const uint2*)&M[(size_t)idx[j] * 64 + cg * 8];

    float a[8], b[8];
#pragma unroll
    for (int j = 0; j < 8; ++j) { a[j] = 0.f; b[j] = 0.f; }
#pragma unroll
    for (int j = 0; j < 16; ++j)
        fp8x8fma((j & 1) ? b : a, w[j], (j < c) ? 1.f : 0.f);

    gather_tail(M, bv, c, cg, a, b);
#pragma unroll
    for (int j = 0; j < 8; ++j) acc8[j] = a[j] + b[j];
}

// Two-node fused deep gather (mm_gather): both halves' cnt+csr issued
// together, then all 32 M-loads in flight before any FMA. Doubles
// per-thread MLP vs calling gather_deep twice.
__device__ __forceinline__ void gather_deep2(
    const unsigned char* __restrict__ M, const int* __restrict__ cnt,
    const unsigned short* __restrict__ csr, int node0, int node1, int cg,
    float* o0, float* o1, int N)
{
    const int n0 = node0 < N ? node0 : 0;
    const int n1 = node1 < N ? node1 : 0;
    int c0 = node0 < N ? cnt[n0] : 0;
    int c1 = node1 < N ? cnt[n1] : 0;
    if (c0 > CAP) c0 = CAP;
    if (c1 > CAP) c1 = CAP;
    const uint4* bv0 = (const uint4*)(csr + (size_t)n0 * CAP);
    const uint4* bv1 = (const uint4*)(csr + (size_t)n1 * CAP);

    uint4 p0 = bv0[0], p1 = bv0[1];
    uint4 q0 = bv1[0], q1 = bv1[1];
    unsigned ia[16], ib[16];
    unpack16(p0, p1, ia);
    unpack16(q0, q1, ib);
#pragma unroll
    for (int j = 0; j < 16; ++j) {
        if (j >= c0) ia[j] = 0;
        if (j >= c1) ib[j] = 0;
    }

    uint2 w0[16], w1[16];
#pragma unroll
    for (int j = 0; j < 16; ++j)
        w0[j] = *(const uint2*)&M[(size_t)ia[j] * 64 + cg * 8];
#pragma unroll
    for (int j = 0; j < 16; ++j)
        w1[j] = *(const uint2*)&M[(size_t)ib[j] * 64 + cg * 8];

    float a0[8], b0[8], a1[8], b1[8];
#pragma unroll
    for (int j = 0; j < 8; ++j) { a0[j] = 0.f; b0[j] = 0.f; a1[j] = 0.f; b1[j] = 0.f; }
#pragma unroll
    for (int j = 0; j < 16; ++j)
        fp8x8fma((j & 1) ? b0 : a0, w0[j], (j < c0) ? 1.f : 0.f);
#pragma unroll
    for (int j = 0; j < 16; ++j)
        fp8x8fma((j & 1) ? b1 : a1, w1[j], (j < c1) ? 1.f : 0.f);

    gather_tail(M, bv0, c0, cg, a0, b0);
    gather_tail(M, bv1, c1, cg, a1, b1);
#pragma unroll
    for (int j = 0; j < 8; ++j) { o0[j] = a0[j] + b0[j]; o1[j] = a1[j] + b1[j]; }
}

// ---------------- layer 1: [bucket fill || mm1 (MFMA)] ----------------

__device__ __forceinline__ void mm1_body(
    const float* __restrict__ Xraw,
    const float* __restrict__ W1, const float* __restrict__ W2,
    unsigned short* __restrict__ S, unsigned char* __restrict__ M,
    int N, int blk)
{
    __shared__ __align__(16) unsigned short Xs[64][72];
    __shared__ __align__(16) unsigned short Ws[128][72];
    const int tid  = threadIdx.x;
    const int lane = tid & 63;
    const int wv   = tid >> 6;
    const int lrow = lane & 15;
    const int quad = lane >> 4;
    const int row0 = blk * 64;

    floatx4 acc[8];
#pragma unroll
    for (int i = 0; i < 8; ++i) acc[i] = (floatx4){0.f, 0.f, 0.f, 0.f};

    const int xr  = tid >> 2;
    const int xk  = (tid & 3) * 16;
    const int gxr = row0 + xr;

    for (int ko = 0; ko < 128; ko += 64) {
#pragma unroll
        for (int q = 0; q < 4; ++q) {
            float4 v = make_float4(0.f, 0.f, 0.f, 0.f);
            if (gxr < N) v = *(const float4*)&Xraw[(size_t)gxr * 128 + ko + xk + q * 4];
            ushort4 p;
            p.x = f2bf(v.x); p.y = f2bf(v.y); p.z = f2bf(v.z); p.w = f2bf(v.w);
            *(ushort4*)&Xs[xr][xk + q * 4] = p;
        }
#pragma unroll
        for (int i = 0; i < 2; ++i) {
            int s  = tid + i * 256;
            int k0 = (s & 15) * 4;
            int c0 = (s >> 4) * 4;
            float wr[4][4];
#pragma unroll
            for (int r = 0; r < 4; ++r) {
                int gk = ko + k0 + r;
                float4 t4 = (c0 < 64) ? *(const float4*)&W1[(size_t)gk * 64 + c0]
                                      : *(const float4*)&W2[(size_t)gk * 64 + (c0 - 64)];
                wr[r][0] = t4.x; wr[r][1] = t4.y; wr[r][2] = t4.z; wr[r][3] = t4.w;
            }
#pragma unroll
            for (int j = 0; j < 4; ++j) {
                ushort4 col;
                col.x = f2bf(wr[0][j]); col.y = f2bf(wr[1][j]);
                col.z = f2bf(wr[2][j]); col.w = f2bf(wr[3][j]);
                *(ushort4*)&Ws[c0 + j][k0] = col;
            }
        }
        __syncthreads();

#pragma unroll
        for (int kc = 0; kc < 2; ++kc) {
            int kofs = kc * 32 + quad * 8;
            short8 a = *(const short8*)&Xs[wv * 16 + lrow][kofs];
#pragma unroll
            for (int ct = 0; ct < 8; ++ct) {
                short8 b = *(const short8*)&Ws[ct * 16 + lrow][kofs];
                acc[ct] = __builtin_amdgcn_mfma_f32_16x16x32_bf16(a, b, acc[ct], 0, 0, 0);
            }
        }
        __syncthreads();
    }

    const int orow = row0 + wv * 16 + quad * 4;
#pragma unroll
    for (int ct = 0; ct < 8; ++ct) {
        int col = ct * 16 + lrow;
#pragma unroll
        for (int r = 0; r < 4; ++r) {
            int gr = orow + r;
            if (gr < N) {
                if (ct < 4) S[(size_t)gr * 64 + col] = f2bf(acc[ct][r]);
                else        M[(size_t)gr * 64 + (col - 64)] = f2fp8(acc[ct][r]);
            }
        }
    }
}

// One-pass bucket fill, ILP-8 (R9-proven).
__device__ __forceinline__ void fill_body(
    const int* __restrict__ ei, int* __restrict__ cnt,
    unsigned short* __restrict__ csr, int E, int bid, int stride)
{
    int base = bid * 256 + threadIdx.x;
    int e[8], d[8], s[8], p[8];
    bool v[8];
#pragma unroll
    for (int j = 0; j < 8; ++j) {
        e[j] = base + j * stride;
        v[j] = e[j] < E;
        if (v[j]) {
            d[j] = ei[E + e[j]];
            s[j] = ei[e[j]];
        }
    }
#pragma unroll
    for (int j = 0; j < 8; ++j)
        if (v[j]) p[j] = atomicAdd(&cnt[d[j]], 1);
#pragma unroll
    for (int j = 0; j < 8; ++j)
        if (v[j] && p[j] < CAP) csr[(size_t)d[j] * CAP + p[j]] = (unsigned short)s[j];
}

__global__ __launch_bounds__(256) void mm1_fill_kernel(
    const float* __restrict__ Xraw,
    const float* __restrict__ W1, const float* __restrict__ W2,
    unsigned short* __restrict__ S, unsigned char* __restrict__ M, int N,
    const int* __restrict__ ei, int* __restrict__ cnt,
    unsigned short* __restrict__ csr, int E, int edgeBlocks)
{
    if ((int)blockIdx.x < edgeBlocks) {
        fill_body(ei, cnt, csr, E, blockIdx.x, edgeBlocks * 256);
    } else {
        mm1_body(Xraw, W1, W2, S, M, N, (int)blockIdx.x - edgeBlocks);
    }
}

// ---------------- layers 2,3: gather fused into GEMM staging ----------------
// 256 threads, 32 slots x 2 rows; both rows' gathers fused (gather_deep2).
__global__ __launch_bounds__(256) void mm_gather_kernel(
    const unsigned short* __restrict__ Sprev, const unsigned char* __restrict__ Mprev,
    const int* __restrict__ cnt, const unsigned short* __restrict__ csr,
    const float* __restrict__ W1, const float* __restrict__ W2,
    unsigned short* __restrict__ Sout, unsigned char* __restrict__ Mout, int N)
{
    __shared__ __align__(16) unsigned short Xs[64][72];
    __shared__ __align__(16) unsigned short Ws[128][72];
    const int tid  = threadIdx.x;
    const int lane = tid & 63;
    const int wv   = tid >> 6;
    const int lrow = lane & 15;
    const int quad = lane >> 4;
    const int row0 = blockIdx.x * 64;
    const int eg   = lane >> 3;
    const int cg   = lane & 7;

    // ---- stage W (64k x 128c, transposed bf16) ----
#pragma unroll
    for (int i = 0; i < 2; ++i) {
        int s  = tid + i * 256;
        int k0 = (s & 15) * 4;
        int c0 = (s >> 4) * 4;
        float wr[4][4];
#pragma unroll
        for (int r = 0; r < 4; ++r) {
            int gk = k0 + r;
            float4 t4 = (c0 < 64) ? *(const float4*)&W1[(size_t)gk * 64 + c0]
                                  : *(const float4*)&W2[(size_t)gk * 64 + (c0 - 64)];
            wr[r][0] = t4.x; wr[r][1] = t4.y; wr[r][2] = t4.z; wr[r][3] = t4.w;
        }
#pragma unroll
        for (int j = 0; j < 4; ++j) {
            ushort4 col;
            col.x = f2bf(wr[0][j]); col.y = f2bf(wr[1][j]);
            col.z = f2bf(wr[2][j]); col.w = f2bf(wr[3][j]);
            *(ushort4*)&Ws[c0 + j][k0] = col;
        }
    }

    // ---- gather-stage X: act = relu(self + gather(msg)) -> bf16 LDS ----
    {
        const int xrow0 = wv * 8 + eg;
        const int xrow1 = 32 + wv * 8 + eg;
        const int node0 = row0 + xrow0;
        const int node1 = row0 + xrow1;

        // issue self-loads first (independent of gathers)
        const int s0 = node0 < N ? node0 : 0;
        const int s1 = node1 < N ? node1 : 0;
        uint4 h0 = *(const uint4*)&Sprev[(size_t)s0 * 64 + cg * 8];
        uint4 h1 = *(const uint4*)&Sprev[(size_t)s1 * 64 + cg * 8];

        float g0[8], g1[8];
        gather_deep2(Mprev, cnt, csr, node0, node1, cg, g0, g1, N);

        float r0[8], r1[8], s8[8];
        bf8unpack(h0, s8);
#pragma unroll
        for (int j = 0; j < 8; ++j)
            r0[j] = (node0 < N) ? fmaxf(g0[j] + s8[j], 0.f) : 0.f;
        bf8unpack(h1, s8);
#pragma unroll
        for (int j = 0; j < 8; ++j)
            r1[j] = (node1 < N) ? fmaxf(g1[j] + s8[j], 0.f) : 0.f;

        ushort4 p0, p1;
        p0.x = f2bf(r0[0]); p0.y = f2bf(r0[1]); p0.z = f2bf(r0[2]); p0.w = f2bf(r0[3]);
        p1.x = f2bf(r0[4]); p1.y = f2bf(r0[5]); p1.z = f2bf(r0[6]); p1.w = f2bf(r0[7]);
        *(ushort4*)&Xs[xrow0][cg * 8]     = p0;
        *(ushort4*)&Xs[xrow0][cg * 8 + 4] = p1;
        p0.x = f2bf(r1[0]); p0.y = f2bf(r1[1]); p0.z = f2bf(r1[2]); p0.w = f2bf(r1[3]);
        p1.x = f2bf(r1[4]); p1.y = f2bf(r1[5]); p1.z = f2bf(r1[6]); p1.w = f2bf(r1[7]);
        *(ushort4*)&Xs[xrow1][cg * 8]     = p0;
        *(ushort4*)&Xs[xrow1][cg * 8 + 4] = p1;
    }
    __syncthreads();

    // ---- MFMA ----
    floatx4 acc[8];
#pragma unroll
    for (int i = 0; i < 8; ++i) acc[i] = (floatx4){0.f, 0.f, 0.f, 0.f};
#pragma unroll
    for (int kc = 0; kc < 2; ++kc) {
        int kofs = kc * 32 + quad * 8;
        short8 a = *(const short8*)&Xs[wv * 16 + lrow][kofs];
#pragma unroll
        for (int ct = 0; ct < 8; ++ct) {
            short8 b = *(const short8*)&Ws[ct * 16 + lrow][kofs];
            acc[ct] = __builtin_amdgcn_mfma_f32_16x16x32_bf16(a, b, acc[ct], 0, 0, 0);
        }
    }

    // ---- epilogue: bf16 self row + fp8 msg row per output node ----
    const int orow = row0 + wv * 16 + quad * 4;
#pragma unroll
    for (int ct = 0; ct < 8; ++ct) {
        int col = ct * 16 + lrow;
#pragma unroll
        for (int r = 0; r < 4; ++r) {
            int gr = orow + r;
            if (gr < N) {
                if (ct < 4) Sout[(size_t)gr * 64 + col] = f2bf(acc[ct][r]);
                else        Mout[(size_t)gr * 64 + (col - 64)] = f2fp8(acc[ct][r]);
            }
        }
    }
}

// ---------------- pool + deep gather + classifier ----------------
// One block (512 threads, 64 node-slots) per graph; lane owns 8 cols.
__global__ __launch_bounds__(512) void pool_gather_cls_kernel(
    const unsigned short* __restrict__ S, const unsigned char* __restrict__ M,
    const int* __restrict__ cnt, const unsigned short* __restrict__ csr,
    const int* __restrict__ batch,
    const float* __restrict__ cW1, const float* __restrict__ cb1,
    const float* __restrict__ cW2, const float* __restrict__ cb2,
    float* __restrict__ out, int N)
{
    int g  = blockIdx.x;
    int t  = threadIdx.x;
    int wv = t >> 6;
    int lane = t & 63;
    int eg = lane >> 3;
    int cg = lane & 7;
    int slot = wv * 8 + eg;      // 0..63

    int lo = 0, hi = N;
    while (lo < hi) { int mid = (lo + hi) >> 1; if (batch[mid] < g) lo = mid + 1; else hi = mid; }
    int start = lo;
    hi = N;
    while (lo < hi) { int mid = (lo + hi) >> 1; if (batch[mid] < g + 1) lo = mid + 1; else hi = mid; }
    int end = lo;

    float p8[8];
#pragma unroll
    for (int j = 0; j < 8; ++j) p8[j] = 0.f;

    for (int r = start + slot; r < end; r += 64) {
        float g8[8];
        gather_deep(M, cnt, csr, r, cg, g8, N);
        uint4 h = *(const uint4*)&S[(size_t)r * 64 + cg * 8];
        float s8[8];
        bf8unpack(h, s8);
#pragma unroll
        for (int j = 0; j < 8; ++j) p8[j] += fmaxf(g8[j] + s8[j], 0.f);
    }

    __shared__ float part[64][64];
    __shared__ float pooled[64];
#pragma unroll
    for (int j = 0; j < 8; ++j) part[slot][cg * 8 + j] = p8[j];
    __syncthreads();

    if (t < 64) {
        float s = 0.f;
#pragma unroll 8
        for (int k = 0; k < 64; ++k) s += part[k][t];
        float c_ = (float)((end - start) > 0 ? (end - start) : 1);
        pooled[t] = s / c_;
    }
    __syncthreads();
    if (t < 64) {
        float a = cb1[t];
#pragma unroll 8
        for (int k = 0; k < 64; ++k) a += pooled[k] * cW1[k * 64 + t];
        a = fmaxf(a, 0.f);
        float o = a * cW2[t];
#pragma unroll
        for (int off_ = 32; off_ > 0; off_ >>= 1) o += __shfl_down(o, off_);
        if (t == 0) out[g] = o + cb2[0];
    }
}

extern "C" void kernel_launch(void* const* d_in, const int* in_sizes, int n_in,
                              void* d_out, int out_size, void* d_ws, size_t ws_size,
                              hipStream_t stream)
{
    const float* x     = (const float*)d_in[0];
    const int*   ei    = (const int*)d_in[1];
    const int*   batch = (const int*)d_in[2];
    const float* W1_1  = (const float*)d_in[3];
    const float* W2_1  = (const float*)d_in[4];
    const float* W1_2  = (const float*)d_in[5];
    const float* W2_2  = (const float*)d_in[6];
    const float* W1_3  = (const float*)d_in[7];
    const float* W2_3  = (const float*)d_in[8];
    const float* cW1   = (const float*)d_in[9];
    const float* cb1   = (const float*)d_in[10];
    const float* cW2   = (const float*)d_in[11];
    const float* cb2   = (const float*)d_in[12];
    float* out = (float*)d_out;

    const int N = in_sizes[0] / 128;
    const int E = in_sizes[1] / 2;
    const int G = out_size;

    // Workspace layout (all dereferenced gather idx < N after R18 clamp):
    //   MA[N][64] fp8 | MB[N][64] fp8 | SA[N][64] bf16 | SB[N][64] bf16
    //   | cnt[N] | csr[N][CAP] u16      (total ~25.8 MB)
    unsigned char*  MA  = (unsigned char*)d_ws;                     // N*64 fp8
    unsigned char*  MB  = MA + (size_t)N * 64;                      // N*64 fp8
    unsigned short* SA  = (unsigned short*)(MB + (size_t)N * 64);   // N*64 bf16
    unsigned short* SB  = SA + (size_t)N * 64;                      // N*64 bf16
    int*            cnt = (int*)(SB + (size_t)N * 64);              // N
    unsigned short* csr = (unsigned short*)(cnt + N);               // N*CAP

    const int mmGrid     = (N + 63) / 64;
    const int edgeBlocks = (E + 2047) / 2048;    // ILP-8

    (void)hipMemsetAsync(cnt, 0, (size_t)N * sizeof(int), stream);

    // layer 1: [bucket fill || mm1] -> SA,MA
    mm1_fill_kernel<<<edgeBlocks + mmGrid, 256, 0, stream>>>(
        x, W1_1, W2_1, SA, MA, N, ei, cnt, csr, E, edgeBlocks);
    // layer 2: gather(MA) fused into GEMM -> SB,MB
    mm_gather_kernel<<<mmGrid, 256, 0, stream>>>(
        SA, MA, cnt, csr, W1_2, W2_2, SB, MB, N);
    // layer 3: gather(MB) fused into GEMM -> SA,MA
    mm_gather_kernel<<<mmGrid, 256, 0, stream>>>(
        SB, MB, cnt, csr, W1_3, W2_3, SA, MA, N);
    // pool (gather(MA) + relu(self+.) mean) + classifier
    pool_gather_cls_kernel<<<G, 512, 0, stream>>>(
        SA, MA, cnt, csr, batch, cW1, cb1, cW2, cb2, out, N);
}

// Round 9
// 200.541 us; speedup vs baseline: 1.0785x; 1.0252x over previous
//
#include <hip/hip_runtime.h>

// ---------------------------------------------------------------------------
// GNN discriminator, 5 dispatches:
//   memset csrx -> [bucket-fill || mm1] -> mm2+gather -> mm3+gather
//   -> pool+gather+classifier
// S[N][64] bf16 (self) + M[N][64] fp8-e4m3 (message) split (R19).
// R23: the pipeline is bound by random 64B LINE transactions (~13-17
// lines/cyc chip-wide in every dispatch), not bytes: fp8 (-50% bytes) was
// only -9us, MLP x2 (R22) and cache hints (R15/R21) were null. So cut
// lines: csrx[node] = 128B row [u32 count | 62 u16 slots]. Fill's atomic
// and slot store now hit the SAME line (p<30 for >99.9% of edges):
// fill random line-ops ~halved (was: cnt atomic line + csr store line).
// Gather reads ONE line per node (count+30 slots) instead of three
// (cnt + 2 csr lines); line 1 (slots 30..61) only for deg>30 (~0.1%).
// Word0 only written by atomics, slots only by ticketed stores ->
// byte-masked writebacks merge safely (same mechanism as old csr).
// NSLOT=62 vs old CAP=64: P(deg>62)~0, no edge loss.
// History: R22 2-node-fused gather NEUTRAL (MLP not the lever). R21 nt
// REGRESSED. R19 fp8 msg -9us (kept). R18 idx clamp kept (idx<N safety).
// Fill atomic floor R6-R12; R10 exec-predication regresses; R14 >32
// slots/block regresses.
// ---------------------------------------------------------------------------

#define NSLOT 62   // u16 slots per 128B row; word0 = atomic count

typedef __attribute__((ext_vector_type(8))) short short8;   // 8 bf16 (4 VGPR)
typedef __attribute__((ext_vector_type(4))) float floatx4;  // MFMA C/D
typedef __attribute__((ext_vector_type(2))) float floatx2;  // cvt_pk result

__device__ __forceinline__ unsigned short f2bf(float f) {
    union { float f; unsigned u; } v; v.f = f;
    unsigned r = v.u + 0x7FFF + ((v.u >> 16) & 1);   // round-to-nearest-even
    return (unsigned short)(r >> 16);
}

// f32 -> fp8 e4m3 (OCP, RNE) via packed HW convert; take byte 0.
__device__ __forceinline__ unsigned char f2fp8(float f) {
    int v = __builtin_amdgcn_cvt_pk_fp8_f32(f, 0.f, 0, false);
    return (unsigned char)(v & 0xff);
}

// 8 fp8 (packed in uint2) -> f32, fmaf-accumulate with scale s.
__device__ __forceinline__ void fp8x8fma(float* t, uint2 w, float s) {
    floatx2 p;
    p = __builtin_amdgcn_cvt_pk_f32_fp8(w.x, false);
    t[0] = fmaf(p[0], s, t[0]); t[1] = fmaf(p[1], s, t[1]);
    p = __builtin_amdgcn_cvt_pk_f32_fp8(w.x, true);
    t[2] = fmaf(p[0], s, t[2]); t[3] = fmaf(p[1], s, t[3]);
    p = __builtin_amdgcn_cvt_pk_f32_fp8(w.y, false);
    t[4] = fmaf(p[0], s, t[4]); t[5] = fmaf(p[1], s, t[5]);
    p = __builtin_amdgcn_cvt_pk_f32_fp8(w.y, true);
    t[6] = fmaf(p[0], s, t[6]); t[7] = fmaf(p[1], s, t[7]);
}

__device__ __forceinline__ void bf8unpack(uint4 w, float* s) {
    s[0] = __uint_as_float(w.x << 16);
    s[1] = __uint_as_float(w.x & 0xffff0000u);
    s[2] = __uint_as_float(w.y << 16);
    s[3] = __uint_as_float(w.y & 0xffff0000u);
    s[4] = __uint_as_float(w.z << 16);
    s[5] = __uint_as_float(w.z & 0xffff0000u);
    s[6] = __uint_as_float(w.w << 16);
    s[7] = __uint_as_float(w.w & 0xffff0000u);
}

// Deep gather over M (fp8 msg rows, 64B) using the 128B combined row:
// ONE random line read gives count + 30 slot indices; up to 30 M-loads in
// flight, fmaf-masked. Masked slots read index 0 (zeroed slots + clamp).
__device__ __forceinline__ void gather_row(
    const unsigned char* __restrict__ M, const unsigned short* __restrict__ csrx,
    int node, int cg, float* acc8, int N)
{
    const int nodeC = node < N ? node : 0;
    const uint4* bv = (const uint4*)(csrx + (size_t)nodeC * 64);
    uint4 q0 = bv[0], q1 = bv[1], q2 = bv[2], q3 = bv[3];   // line 0 (64B)
    int c = node < N ? (int)q0.x : 0;
    if (c > NSLOT) c = NSLOT;

    unsigned ia[16], ib[14];
    ia[0]  = q0.y & 0xffff; ia[1]  = q0.y >> 16;
    ia[2]  = q0.z & 0xffff; ia[3]  = q0.z >> 16;
    ia[4]  = q0.w & 0xffff; ia[5]  = q0.w >> 16;
    ia[6]  = q1.x & 0xffff; ia[7]  = q1.x >> 16;
    ia[8]  = q1.y & 0xffff; ia[9]  = q1.y >> 16;
    ia[10] = q1.z & 0xffff; ia[11] = q1.z >> 16;
    ia[12] = q1.w & 0xffff; ia[13] = q1.w >> 16;
    ia[14] = q2.x & 0xffff; ia[15] = q2.x >> 16;
    ib[0]  = q2.y & 0xffff; ib[1]  = q2.y >> 16;
    ib[2]  = q2.z & 0xffff; ib[3]  = q2.z >> 16;
    ib[4]  = q2.w & 0xffff; ib[5]  = q2.w >> 16;
    ib[6]  = q3.x & 0xffff; ib[7]  = q3.x >> 16;
    ib[8]  = q3.y & 0xffff; ib[9]  = q3.y >> 16;
    ib[10] = q3.z & 0xffff; ib[11] = q3.z >> 16;
    ib[12] = q3.w & 0xffff; ib[13] = q3.w >> 16;

#pragma unroll
    for (int j = 0; j < 16; ++j) if (j >= c) ia[j] = 0;
#pragma unroll
    for (int j = 0; j < 14; ++j) if (16 + j >= c) ib[j] = 0;

    uint2 wa[16];
#pragma unroll
    for (int j = 0; j < 16; ++j)
        wa[j] = *(const uint2*)&M[(size_t)ia[j] * 64 + cg * 8];
    uint2 wb[14];
#pragma unroll
    for (int j = 0; j < 14; ++j)
        wb[j] = *(const uint2*)&M[(size_t)ib[j] * 64 + cg * 8];

    float a[8], b[8];
#pragma unroll
    for (int j = 0; j < 8; ++j) { a[j] = 0.f; b[j] = 0.f; }
#pragma unroll
    for (int j = 0; j < 16; ++j)
        fp8x8fma((j & 1) ? b : a, wa[j], (j < c) ? 1.f : 0.f);
#pragma unroll
    for (int j = 0; j < 14; ++j)
        fp8x8fma((j & 1) ? b : a, wb[j], (16 + j < c) ? 1.f : 0.f);

    // rare tail (deg > 30, ~0.1% of nodes): slots 30..61 in line 1.
    for (int base = 30; base < c; base += 8) {
        uint4 q = bv[4 + ((base - 30) >> 3)];
        unsigned id2[8];
        id2[0] = q.x & 0xffff; id2[1] = q.x >> 16;
        id2[2] = q.y & 0xffff; id2[3] = q.y >> 16;
        id2[4] = q.z & 0xffff; id2[5] = q.z >> 16;
        id2[6] = q.w & 0xffff; id2[7] = q.w >> 16;
#pragma unroll
        for (int j = 0; j < 8; ++j)
            if (base + j >= c) id2[j] = 0;
        uint2 w2[8];
#pragma unroll
        for (int j = 0; j < 8; ++j)
            w2[j] = *(const uint2*)&M[(size_t)id2[j] * 64 + cg * 8];
#pragma unroll
        for (int j = 0; j < 8; ++j)
            fp8x8fma((j & 1) ? b : a, w2[j], (base + j < c) ? 1.f : 0.f);
    }
#pragma unroll
    for (int j = 0; j < 8; ++j) acc8[j] = a[j] + b[j];
}

// ---------------- layer 1: [bucket fill || mm1 (MFMA)] ----------------

__device__ __forceinline__ void mm1_body(
    const float* __restrict__ Xraw,
    const float* __restrict__ W1, const float* __restrict__ W2,
    unsigned short* __restrict__ S, unsigned char* __restrict__ M,
    int N, int blk)
{
    __shared__ __align__(16) unsigned short Xs[64][72];
    __shared__ __align__(16) unsigned short Ws[128][72];
    const int tid  = threadIdx.x;
    const int lane = tid & 63;
    const int wv   = tid >> 6;
    const int lrow = lane & 15;
    const int quad = lane >> 4;
    const int row0 = blk * 64;

    floatx4 acc[8];
#pragma unroll
    for (int i = 0; i < 8; ++i) acc[i] = (floatx4){0.f, 0.f, 0.f, 0.f};

    const int xr  = tid >> 2;
    const int xk  = (tid & 3) * 16;
    const int gxr = row0 + xr;

    for (int ko = 0; ko < 128; ko += 64) {
#pragma unroll
        for (int q = 0; q < 4; ++q) {
            float4 v = make_float4(0.f, 0.f, 0.f, 0.f);
            if (gxr < N) v = *(const float4*)&Xraw[(size_t)gxr * 128 + ko + xk + q * 4];
            ushort4 p;
            p.x = f2bf(v.x); p.y = f2bf(v.y); p.z = f2bf(v.z); p.w = f2bf(v.w);
            *(ushort4*)&Xs[xr][xk + q * 4] = p;
        }
#pragma unroll
        for (int i = 0; i < 2; ++i) {
            int s  = tid + i * 256;
            int k0 = (s & 15) * 4;
            int c0 = (s >> 4) * 4;
            float wr[4][4];
#pragma unroll
            for (int r = 0; r < 4; ++r) {
                int gk = ko + k0 + r;
                float4 t4 = (c0 < 64) ? *(const float4*)&W1[(size_t)gk * 64 + c0]
                                      : *(const float4*)&W2[(size_t)gk * 64 + (c0 - 64)];
                wr[r][0] = t4.x; wr[r][1] = t4.y; wr[r][2] = t4.z; wr[r][3] = t4.w;
            }
#pragma unroll
            for (int j = 0; j < 4; ++j) {
                ushort4 col;
                col.x = f2bf(wr[0][j]); col.y = f2bf(wr[1][j]);
                col.z = f2bf(wr[2][j]); col.w = f2bf(wr[3][j]);
                *(ushort4*)&Ws[c0 + j][k0] = col;
            }
        }
        __syncthreads();

#pragma unroll
        for (int kc = 0; kc < 2; ++kc) {
            int kofs = kc * 32 + quad * 8;
            short8 a = *(const short8*)&Xs[wv * 16 + lrow][kofs];
#pragma unroll
            for (int ct = 0; ct < 8; ++ct) {
                short8 b = *(const short8*)&Ws[ct * 16 + lrow][kofs];
                acc[ct] = __builtin_amdgcn_mfma_f32_16x16x32_bf16(a, b, acc[ct], 0, 0, 0);
            }
        }
        __syncthreads();
    }

    const int orow = row0 + wv * 16 + quad * 4;
#pragma unroll
    for (int ct = 0; ct < 8; ++ct) {
        int col = ct * 16 + lrow;
#pragma unroll
        for (int r = 0; r < 4; ++r) {
            int gr = orow + r;
            if (gr < N) {
                if (ct < 4) S[(size_t)gr * 64 + col] = f2bf(acc[ct][r]);
                else        M[(size_t)gr * 64 + (col - 64)] = f2fp8(acc[ct][r]);
            }
        }
    }
}

// One-pass bucket fill, ILP-8 (R9-proven). Atomic ticket (row word0) and
// slot store land in the SAME 64B line for p<30 (>99.9% of edges).
__device__ __forceinline__ void fill_body(
    const int* __restrict__ ei, unsigned short* __restrict__ csrx,
    int E, int bid, int stride)
{
    int base = bid * 256 + threadIdx.x;
    int e[8], d[8], s[8], p[8];
    bool v[8];
#pragma unroll
    for (int j = 0; j < 8; ++j) {
        e[j] = base + j * stride;
        v[j] = e[j] < E;
        if (v[j]) {
            d[j] = ei[E + e[j]];
            s[j] = ei[e[j]];
        }
    }
#pragma unroll
    for (int j = 0; j < 8; ++j)
        if (v[j]) p[j] = atomicAdd((int*)(csrx + (size_t)d[j] * 64), 1);
#pragma unroll
    for (int j = 0; j < 8; ++j)
        if (v[j] && p[j] < NSLOT) csrx[(size_t)d[j] * 64 + 2 + p[j]] = (unsigned short)s[j];
}

__global__ __launch_bounds__(256) void mm1_fill_kernel(
    const float* __restrict__ Xraw,
    const float* __restrict__ W1, const float* __restrict__ W2,
    unsigned short* __restrict__ S, unsigned char* __restrict__ M, int N,
    const int* __restrict__ ei, unsigned short* __restrict__ csrx,
    int E, int edgeBlocks)
{
    if ((int)blockIdx.x < edgeBlocks) {
        fill_body(ei, csrx, E, blockIdx.x, edgeBlocks * 256);
    } else {
        mm1_body(Xraw, W1, W2, S, M, N, (int)blockIdx.x - edgeBlocks);
    }
}

// ---------------- layers 2,3: gather fused into GEMM staging ----------------
// 256 threads, 32 slots x 2 rows (R13-proven best shape).
__global__ __launch_bounds__(256) void mm_gather_kernel(
    const unsigned short* __restrict__ Sprev, const unsigned char* __restrict__ Mprev,
    const unsigned short* __restrict__ csrx,
    const float* __restrict__ W1, const float* __restrict__ W2,
    unsigned short* __restrict__ Sout, unsigned char* __restrict__ Mout, int N)
{
    __shared__ __align__(16) unsigned short Xs[64][72];
    __shared__ __align__(16) unsigned short Ws[128][72];
    const int tid  = threadIdx.x;
    const int lane = tid & 63;
    const int wv   = tid >> 6;
    const int lrow = lane & 15;
    const int quad = lane >> 4;
    const int row0 = blockIdx.x * 64;
    const int eg   = lane >> 3;
    const int cg   = lane & 7;

    // ---- stage W (64k x 128c, transposed bf16) ----
#pragma unroll
    for (int i = 0; i < 2; ++i) {
        int s  = tid + i * 256;
        int k0 = (s & 15) * 4;
        int c0 = (s >> 4) * 4;
        float wr[4][4];
#pragma unroll
        for (int r = 0; r < 4; ++r) {
            int gk = k0 + r;
            float4 t4 = (c0 < 64) ? *(const float4*)&W1[(size_t)gk * 64 + c0]
                                  : *(const float4*)&W2[(size_t)gk * 64 + (c0 - 64)];
            wr[r][0] = t4.x; wr[r][1] = t4.y; wr[r][2] = t4.z; wr[r][3] = t4.w;
        }
#pragma unroll
        for (int j = 0; j < 4; ++j) {
            ushort4 col;
            col.x = f2bf(wr[0][j]); col.y = f2bf(wr[1][j]);
            col.z = f2bf(wr[2][j]); col.w = f2bf(wr[3][j]);
            *(ushort4*)&Ws[c0 + j][k0] = col;
        }
    }

    // ---- gather-stage X: act = relu(self + gather(msg)) -> bf16 LDS ----
#pragma unroll
    for (int half = 0; half < 2; ++half) {
        int xrow = half * 32 + wv * 8 + eg;
        int node = row0 + xrow;
        float g8[8];
        gather_row(Mprev, csrx, node, cg, g8, N);
        float r8[8];
        if (node < N) {
            uint4 h = *(const uint4*)&Sprev[(size_t)node * 64 + cg * 8];
            float s8[8];
            bf8unpack(h, s8);
#pragma unroll
            for (int j = 0; j < 8; ++j) r8[j] = fmaxf(g8[j] + s8[j], 0.f);
        } else {
#pragma unroll
            for (int j = 0; j < 8; ++j) r8[j] = 0.f;
        }
        ushort4 p0, p1;
        p0.x = f2bf(r8[0]); p0.y = f2bf(r8[1]); p0.z = f2bf(r8[2]); p0.w = f2bf(r8[3]);
        p1.x = f2bf(r8[4]); p1.y = f2bf(r8[5]); p1.z = f2bf(r8[6]); p1.w = f2bf(r8[7]);
        *(ushort4*)&Xs[xrow][cg * 8]     = p0;
        *(ushort4*)&Xs[xrow][cg * 8 + 4] = p1;
    }
    __syncthreads();

    // ---- MFMA ----
    floatx4 acc[8];
#pragma unroll
    for (int i = 0; i < 8; ++i) acc[i] = (floatx4){0.f, 0.f, 0.f, 0.f};
#pragma unroll
    for (int kc = 0; kc < 2; ++kc) {
        int kofs = kc * 32 + quad * 8;
        short8 a = *(const short8*)&Xs[wv * 16 + lrow][kofs];
#pragma unroll
        for (int ct = 0; ct < 8; ++ct) {
            short8 b = *(const short8*)&Ws[ct * 16 + lrow][kofs];
            acc[ct] = __builtin_amdgcn_mfma_f32_16x16x32_bf16(a, b, acc[ct], 0, 0, 0);
        }
    }

    // ---- epilogue: bf16 self row + fp8 msg row per output node ----
    const int orow = row0 + wv * 16 + quad * 4;
#pragma unroll
    for (int ct = 0; ct < 8; ++ct) {
        int col = ct * 16 + lrow;
#pragma unroll
        for (int r = 0; r < 4; ++r) {
            int gr = orow + r;
            if (gr < N) {
                if (ct < 4) Sout[(size_t)gr * 64 + col] = f2bf(acc[ct][r]);
                else        Mout[(size_t)gr * 64 + (col - 64)] = f2fp8(acc[ct][r]);
            }
        }
    }
}

// ---------------- pool + deep gather + classifier ----------------
// One block (512 threads, 64 node-slots) per graph; lane owns 8 cols.
__global__ __launch_bounds__(512) void pool_gather_cls_kernel(
    const unsigned short* __restrict__ S, const unsigned char* __restrict__ M,
    const unsigned short* __restrict__ csrx,
    const int* __restrict__ batch,
    const float* __restrict__ cW1, const float* __restrict__ cb1,
    const float* __restrict__ cW2, const float* __restrict__ cb2,
    float* __restrict__ out, int N)
{
    int g  = blockIdx.x;
    int t  = threadIdx.x;
    int wv = t >> 6;
    int lane = t & 63;
    int eg = lane >> 3;
    int cg = lane & 7;
    int slot = wv * 8 + eg;      // 0..63

    int lo = 0, hi = N;
    while (lo < hi) { int mid = (lo + hi) >> 1; if (batch[mid] < g) lo = mid + 1; else hi = mid; }
    int start = lo;
    hi = N;
    while (lo < hi) { int mid = (lo + hi) >> 1; if (batch[mid] < g + 1) lo = mid + 1; else hi = mid; }
    int end = lo;

    float p8[8];
#pragma unroll
    for (int j = 0; j < 8; ++j) p8[j] = 0.f;

    for (int r = start + slot; r < end; r += 64) {
        float g8[8];
        gather_row(M, csrx, r, cg, g8, N);
        uint4 h = *(const uint4*)&S[(size_t)r * 64 + cg * 8];
        float s8[8];
        bf8unpack(h, s8);
#pragma unroll
        for (int j = 0; j < 8; ++j) p8[j] += fmaxf(g8[j] + s8[j], 0.f);
    }

    __shared__ float part[64][64];
    __shared__ float pooled[64];
#pragma unroll
    for (int j = 0; j < 8; ++j) part[slot][cg * 8 + j] = p8[j];
    __syncthreads();

    if (t < 64) {
        float s = 0.f;
#pragma unroll 8
        for (int k = 0; k < 64; ++k) s += part[k][t];
        float c_ = (float)((end - start) > 0 ? (end - start) : 1);
        pooled[t] = s / c_;
    }
    __syncthreads();
    if (t < 64) {
        float a = cb1[t];
#pragma unroll 8
        for (int k = 0; k < 64; ++k) a += pooled[k] * cW1[k * 64 + t];
        a = fmaxf(a, 0.f);
        float o = a * cW2[t];
#pragma unroll
        for (int off_ = 32; off_ > 0; off_ >>= 1) o += __shfl_down(o, off_);
        if (t == 0) out[g] = o + cb2[0];
    }
}

extern "C" void kernel_launch(void* const* d_in, const int* in_sizes, int n_in,
                              void* d_out, int out_size, void* d_ws, size_t ws_size,
                              hipStream_t stream)
{
    const float* x     = (const float*)d_in[0];
    const int*   ei    = (const int*)d_in[1];
    const int*   batch = (const int*)d_in[2];
    const float* W1_1  = (const float*)d_in[3];
    const float* W2_1  = (const float*)d_in[4];
    const float* W1_2  = (const float*)d_in[5];
    const float* W2_2  = (const float*)d_in[6];
    const float* W1_3  = (const float*)d_in[7];
    const float* W2_3  = (const float*)d_in[8];
    const float* cW1   = (const float*)d_in[9];
    const float* cb1   = (const float*)d_in[10];
    const float* cW2   = (const float*)d_in[11];
    const float* cb2   = (const float*)d_in[12];
    float* out = (float*)d_out;

    const int N = in_sizes[0] / 128;
    const int E = in_sizes[1] / 2;
    const int G = out_size;

    // Workspace layout (all dereferenced gather idx < N after R18 clamp):
    //   MA[N][64] fp8 | MB[N][64] fp8 | SA[N][64] bf16 | SB[N][64] bf16
    //   | csrx[N][64] u16 (128B rows: u32 count + 62 slots)   (~25.6 MB)
    unsigned char*  MA   = (unsigned char*)d_ws;                     // N*64 fp8
    unsigned char*  MB   = MA + (size_t)N * 64;                      // N*64 fp8
    unsigned short* SA   = (unsigned short*)(MB + (size_t)N * 64);   // N*64 bf16
    unsigned short* SB   = SA + (size_t)N * 64;                      // N*64 bf16
    unsigned short* csrx = SB + (size_t)N * 64;                      // N*64 u16

    const int mmGrid     = (N + 63) / 64;
    const int edgeBlocks = (E + 2047) / 2048;    // ILP-8

    // Zero the full csrx (counts + slots): masked gather slots read idx 0.
    (void)hipMemsetAsync(csrx, 0, (size_t)N * 64 * sizeof(unsigned short), stream);

    // layer 1: [bucket fill || mm1] -> SA,MA
    mm1_fill_kernel<<<edgeBlocks + mmGrid, 256, 0, stream>>>(
        x, W1_1, W2_1, SA, MA, N, ei, csrx, E, edgeBlocks);
    // layer 2: gather(MA) fused into GEMM -> SB,MB
    mm_gather_kernel<<<mmGrid, 256, 0, stream>>>(
        SA, MA, csrx, W1_2, W2_2, SB, MB, N);
    // layer 3: gather(MB) fused into GEMM -> SA,MA
    mm_gather_kernel<<<mmGrid, 256, 0, stream>>>(
        SB, MB, csrx, W1_3, W2_3, SA, MA, N);
    // pool (gather(MA) + relu(self+.) mean) + classifier
    pool_gather_cls_kernel<<<G, 512, 0, stream>>>(
        SA, MA, csrx, batch, cW1, cb1, cW2, cb2, out, N);
}